// Round 10
// baseline (193.821 us; speedup 1.0000x reference)
//
#include <hip/hip_runtime.h>

#define T_STEPS 512
#define CHUNK   32
#define NCHUNK  (T_STEPS / CHUNK)   // 16
#define EPB     16                  // elements per 256-thread block (16 lanes/elem)
#define ROWF    132                 // padded row: 33 float4
#define BUFF    (EPB * ROWF)        // 2112 floats per buffer
#define LOG2E   1.4426950408889634f

typedef float v2f __attribute__((ext_vector_type(2)));

// Packed fp32 ops; scalar s broadcast from the LOW half via op_sel_hi
// (numerics verified R5-R9).
__device__ __forceinline__ v2f pk_fma_b(v2f w, float s, v2f c) {
    v2f sv; sv.x = s;
    v2f d;
    asm("v_pk_fma_f32 %0, %1, %2, %3 op_sel_hi:[1,0,1]"
        : "=v"(d) : "v"(w), "v"(sv), "v"(c));
    return d;
}
__device__ __forceinline__ void pk_fma_acc(v2f& a, v2f w, float s) {
    v2f sv; sv.x = s;
    asm("v_pk_fma_f32 %0, %1, %2, %0 op_sel_hi:[1,0,1]"
        : "+v"(a) : "v"(w), "v"(sv));
}
__device__ __forceinline__ v2f pk_mul_b(v2f w, float s) {
    v2f sv; sv.x = s;
    v2f d;
    asm("v_pk_mul_f32 %0, %1, %2 op_sel_hi:[1,0]"
        : "=v"(d) : "v"(w), "v"(sv));
    return d;
}
__device__ __forceinline__ v2f pk_add2(v2f a, v2f b) {
    v2f d;
    asm("v_pk_add_f32 %0, %1, %2" : "=v"(d) : "v"(a), "v"(b));
    return d;
}

// DPP cross-lane (verified R9): xor1=0xB1, xor2=0x4E, xor3=0x1B (quad_perm),
// xor7=row_half_mirror 0x141; xor4/5/6 = quad_perm of s7 (xor group property).
// xor8 within the 16-lane row = row_ror:8 = 0x128.
template <int CTRL>
__device__ __forceinline__ float dppf(float v) {
    return __int_as_float(__builtin_amdgcn_update_dpp(
        0, __float_as_int(v), CTRL, 0xF, 0xF, true));
}

// 16 lanes/elem, gate-split: l = tid&15, j = l&7 (unit), p = l>>3.
// p0 owns unit j's (i,f) rows; p1 owns (g,o). Paired-rcp activations:
// R = rcp((1+eA)(1+eB)) serves both gates; actA = fmaf(eA,dp,cp)*(q2*R)
// gives i' = -2log2e*i (p0) / g (p1) -> ig' = actA * xor8(actA) select-free;
// actB = q1*R gives f (p0) / o (p1) with the SAME formula. c-tail duplicated
// on both halves (ct pre-scaled by -2log2e). h duplicated -> each 8-half is
// self-contained for the next step's matvec. 2048 waves = 2 waves/SIMD:
// the second wave's issue fills the first's trans-chain stalls.
__global__ __launch_bounds__(256, 2) void lstm_kernel(
    const float* __restrict__ x, const float* __restrict__ W_ih,
    const float* __restrict__ W_hh, const float* __restrict__ b_ih,
    const float* __restrict__ b_hh, const float* __restrict__ W_fc,
    const float* __restrict__ b_fc, float* __restrict__ out, int B)
{
    __shared__ float ldsx[2 * BUFF];

    const int tid = threadIdx.x;
    const int e   = tid >> 4;          // block-local element [0,16)
    const int l   = tid & 15;
    const int j   = l & 7;             // hidden unit
    const int p   = l >> 3;            // gate-pair half

    const float nL  = -LOG2E;
    const float n2L = -2.0f * LOG2E;

    // rows: p0 -> A=i(j), B=f(8+j); p1 -> A=g(16+j), B=o(24+j)
    const int rowA = p ? (16 + j) : j;
    const int rowB = p ? (24 + j) : (8 + j);
    const float scA = p ? n2L : nL;    // exp2 arg scale for gate A
    const float scB = nL;              // i,f,o all -log2e
    // actA = fmaf(eA,dp,cp) * (q2*R):  p0 -> -2log2e*i,  p1 -> tanh-num g
    const float cp = p ? 1.0f : n2L;
    const float dp = p ? -1.0f : 0.0f;
    const bool isP1 = (p != 0);

    v2f wih[4], whh[8], bias;
    #pragma unroll
    for (int k = 0; k < 4; ++k)
        wih[k] = v2f{scA * W_ih[rowA * 4 + k], scB * W_ih[rowB * 4 + k]};
    #pragma unroll
    for (int s = 0; s < 8; ++s) {
        const int m = j ^ s;           // unit arriving via xor-s exchange
        whh[s] = v2f{scA * W_hh[rowA * 8 + m], scB * W_hh[rowB * 8 + m]};
    }
    bias = v2f{scA * (b_ih[rowA] + b_hh[rowA]), scB * (b_ih[rowB] + b_hh[rowB])};

    // ---- x staging: 16 elems x 32 steps = 512 float4/chunk; thread covers
    // (se0 + 8q, st) for q=0,1; st = tid&31 q-invariant -> constant offsets.
    const int st  = tid & 31;
    const int se0 = tid >> 5;          // [0,8)
    const float* gp0 = x + (size_t)(blockIdx.x * EPB + se0) * (T_STEPS * 4) + st * 4;
    const int wl0 = se0 * ROWF + st * 4;

    float4 v0, v1;
    v0 = *(const float4*)(gp0);
    v1 = *(const float4*)(gp0 + 8 * 2048);
    *(float4*)&ldsx[wl0 + 0 * 8 * ROWF] = v0;
    *(float4*)&ldsx[wl0 + 1 * 8 * ROWF] = v1;
    v0 = *(const float4*)(gp0 + CHUNK * 4);
    v1 = *(const float4*)(gp0 + CHUNK * 4 + 8 * 2048);
    __syncthreads();

    float h = 0.0f, ct = 0.0f;         // ct = -2log2e * c

    for (int n = 0; n < NCHUNK; ++n) {
        const int wb = ((n + 1) & 1) * BUFF + wl0;
        *(float4*)&ldsx[wb + 0 * 8 * ROWF] = v0;
        *(float4*)&ldsx[wb + 1 * 8 * ROWF] = v1;
        const int t2 = ((n + 2) & (NCHUNK - 1)) * (CHUNK * 4);
        v0 = *(const float4*)(gp0 + t2);
        v1 = *(const float4*)(gp0 + t2 + 8 * 2048);

        const float* xr = &ldsx[(n & 1) * BUFF + e * ROWF];
        float4 xc = *(const float4*)(xr);
        #pragma unroll
        for (int t = 0; t < CHUNK; ++t) {
            const float4 xn = *(const float4*)(xr + (((t + 1) & (CHUNK - 1)) * 4));
            const float4 xt = xc;

            // x-projection (h-independent; fills previous step's trans tail)
            v2f xp = pk_fma_b(wih[0], xt.x, bias);
            pk_fma_acc(xp, wih[1], xt.y);
            pk_fma_acc(xp, wih[2], xt.z);
            pk_fma_acc(xp, wih[3], xt.w);

            // all-DPP h exchange within the 8-half (depth 2)
            const float s1 = dppf<0xB1>(h);
            const float s2 = dppf<0x4E>(h);
            const float s3 = dppf<0x1B>(h);
            const float s7 = dppf<0x141>(h);
            const float s4 = dppf<0x1B>(s7);
            const float s5 = dppf<0x4E>(s7);
            const float s6 = dppf<0xB1>(s7);

            v2f a = pk_fma_b(whh[0], h, xp);
            v2f b = pk_mul_b(whh[1], s1);
            pk_fma_acc(a, whh[2], s2);
            pk_fma_acc(b, whh[3], s3);
            pk_fma_acc(a, whh[4], s4);
            pk_fma_acc(b, whh[5], s5);
            pk_fma_acc(a, whh[6], s6);
            pk_fma_acc(b, whh[7], s7);
            const v2f g2 = pk_add2(a, b);

            const float eA = __builtin_amdgcn_exp2f(g2.x);
            const float eB = __builtin_amdgcn_exp2f(g2.y);
            const float q1 = 1.0f + eA;
            const float q2 = 1.0f + eB;
            const float R  = __builtin_amdgcn_rcpf(q1 * q2);

            const float m_   = q2 * R;               // p0: i,  p1: 1/(1+eG)
            const float tsc  = fmaf(eA, dp, cp);     // p0: -2log2e, p1: 1-eG
            const float actA = tsc * m_;             // p0: i', p1: g
            const float actB = q1 * R;               // p0: f,  p1: o

            const float rA = dppf<0x128>(actA);      // xor8 exchange
            const float rB = dppf<0x128>(actB);

            const float ig = actA * rA;              // -2log2e * i * g (both)
            const float f_ = isP1 ? rB : actB;
            const float o_ = isP1 ? actB : rB;

            ct = fmaf(f_, ct, ig);
            const float eC = __builtin_amdgcn_exp2f(ct);
            const float RC = __builtin_amdgcn_rcpf(1.0f + eC);
            h = o_ * ((1.0f - eC) * RC);             // o * tanh(c)

            xc = xn;
        }
        __syncthreads();
    }

    // out = h . W_fc + b_fc (h duplicated across halves; reduce one 8-half)
    float pr = h * W_fc[j];
    pr += __shfl_xor(pr, 1);
    pr += __shfl_xor(pr, 2);
    pr += __shfl_xor(pr, 4);
    if (l == 0) out[blockIdx.x * EPB + e] = pr + b_fc[0];
}

extern "C" void kernel_launch(void* const* d_in, const int* in_sizes, int n_in,
                              void* d_out, int out_size, void* d_ws, size_t ws_size,
                              hipStream_t stream) {
    const float* x    = (const float*)d_in[0];
    const float* W_ih = (const float*)d_in[1];
    const float* W_hh = (const float*)d_in[2];
    const float* b_ih = (const float*)d_in[3];
    const float* b_hh = (const float*)d_in[4];
    const float* W_fc = (const float*)d_in[5];
    const float* b_fc = (const float*)d_in[6];
    float* out = (float*)d_out;

    const int B = in_sizes[0] / (T_STEPS * 4);   // 8192
    const int block = 256;
    const int grid = (B * 16) / block;           // 512 blocks -> 2 blocks/CU
    lstm_kernel<<<grid, block, 0, stream>>>(x, W_ih, W_hh, b_ih, b_hh, W_fc, b_fc, out, B);
}

// Round 11
// 173.917 us; speedup vs baseline: 1.1144x; 1.1144x over previous
//
#include <hip/hip_runtime.h>

#define T_STEPS 512
#define CHUNK   32
#define NCHUNK  (T_STEPS / CHUNK)   // 16
#define EPB     32                  // elements per 256-thread block
#define ROWF    132                 // padded row: 33 float4 (xt reads bank-conflict-free)
#define BUFF    (EPB * ROWF)        // 4224 floats per buffer
#define LOG2E   1.4426950408889634f

typedef float v2f __attribute__((ext_vector_type(2)));

// Packed fp32 ops; scalar s broadcast from the LOW half via op_sel_hi
// (numerics verified R5-R10).
__device__ __forceinline__ v2f pk_fma_b(v2f w, float s, v2f c) {
    v2f sv; sv.x = s;
    v2f d;
    asm("v_pk_fma_f32 %0, %1, %2, %3 op_sel_hi:[1,0,1]"
        : "=v"(d) : "v"(w), "v"(sv), "v"(c));
    return d;
}
__device__ __forceinline__ void pk_fma_acc(v2f& a, v2f w, float s) {
    v2f sv; sv.x = s;
    asm("v_pk_fma_f32 %0, %1, %2, %0 op_sel_hi:[1,0,1]"
        : "+v"(a) : "v"(w), "v"(sv));
}
__device__ __forceinline__ v2f pk_mul_b(v2f w, float s) {
    v2f sv; sv.x = s;
    v2f d;
    asm("v_pk_mul_f32 %0, %1, %2 op_sel_hi:[1,0]"
        : "=v"(d) : "v"(w), "v"(sv));
    return d;
}
__device__ __forceinline__ v2f pk_add2(v2f a, v2f b) {
    v2f d;
    asm("v_pk_add_f32 %0, %1, %2" : "=v"(d) : "v"(a), "v"(b));
    return d;
}

// All-DPP xor exchange in the 8-lane group (verified R9): xor1=0xB1,
// xor2=0x4E, xor3=0x1B (quad_perm), xor7=row_half_mirror 0x141;
// xor4/5/6 = quad_perm of s7 (xor group property).
template <int CTRL>
__device__ __forceinline__ float dppf(float v) {
    return __int_as_float(__builtin_amdgcn_update_dpp(
        0, __float_as_int(v), CTRL, 0xF, 0xF, true));
}

// 8 lanes/elem; lane j owns unit j's 4 gate rows packed (i,f)/(g,o).
// R11: (a) gate rcps 3->2 via R3 = rcp((1+eI)(1+eG)(1+eF)):
//      f = (1+eI)(1+eG)*R3, ig-num = fma(eG,2L,-2L)*(1+eF)*R3  (exact);
//      (b) next step's x-projection computed BETWEEN this step's gate-exp
//      issue and the R3 tail — guaranteed h-independent filler parked in
//      the ~130-cyc trans-latency bubble (in-order issue needs textual help).
__global__ __launch_bounds__(256) void lstm_kernel(
    const float* __restrict__ x, const float* __restrict__ W_ih,
    const float* __restrict__ W_hh, const float* __restrict__ b_ih,
    const float* __restrict__ b_hh, const float* __restrict__ W_fc,
    const float* __restrict__ b_fc, float* __restrict__ out, int B)
{
    __shared__ float ldsx[2 * BUFF];

    const int tid = threadIdx.x;
    const int e   = tid >> 3;          // block-local element [0,32)
    const int j   = tid & 7;           // hidden unit

    const float nL  = -LOG2E;          // scale for i,f,o rows
    const float n2L = -2.0f * LOG2E;   // scale for g row
    const float P2L =  2.0f * LOG2E;

    // ---- loop-invariant weights (packed gate pairs; W_hh xor-permuted;
    //      exp2 arg scales pre-folded) ----
    const int ri = j, rf = 8 + j, rg = 16 + j, ro = 24 + j;
    v2f wihIF[4], wihGO[4], whhIF[8], whhGO[8], biasIF, biasGO;
    #pragma unroll
    for (int k = 0; k < 4; ++k) {
        wihIF[k] = v2f{nL  * W_ih[ri * 4 + k], nL * W_ih[rf * 4 + k]};
        wihGO[k] = v2f{n2L * W_ih[rg * 4 + k], nL * W_ih[ro * 4 + k]};
    }
    #pragma unroll
    for (int s = 0; s < 8; ++s) {
        const int m = j ^ s;           // unit arriving via xor-s exchange
        whhIF[s] = v2f{nL  * W_hh[ri * 8 + m], nL * W_hh[rf * 8 + m]};
        whhGO[s] = v2f{n2L * W_hh[rg * 8 + m], nL * W_hh[ro * 8 + m]};
    }
    biasIF = v2f{nL  * (b_ih[ri] + b_hh[ri]), nL * (b_ih[rf] + b_hh[rf])};
    biasGO = v2f{n2L * (b_ih[rg] + b_hh[rg]), nL * (b_ih[ro] + b_hh[ro])};

    // ---- x staging (identical to R9): thread covers slots tid + q*256 ----
    const int st  = tid & 31;
    const int se0 = tid >> 5;
    const float* gp0 = x + (size_t)(blockIdx.x * EPB + se0) * (T_STEPS * 4) + st * 4;
    const int wl0 = se0 * ROWF + st * 4;

    float4 v0, v1, v2, v3;
    v0 = *(const float4*)(gp0);
    v1 = *(const float4*)(gp0 + 8 * 2048);
    v2 = *(const float4*)(gp0 + 16 * 2048);
    v3 = *(const float4*)(gp0 + 24 * 2048);
    *(float4*)&ldsx[wl0 + 0 * 8 * ROWF] = v0;
    *(float4*)&ldsx[wl0 + 1 * 8 * ROWF] = v1;
    *(float4*)&ldsx[wl0 + 2 * 8 * ROWF] = v2;
    *(float4*)&ldsx[wl0 + 3 * 8 * ROWF] = v3;
    v0 = *(const float4*)(gp0 + CHUNK * 4);
    v1 = *(const float4*)(gp0 + CHUNK * 4 + 8 * 2048);
    v2 = *(const float4*)(gp0 + CHUNK * 4 + 16 * 2048);
    v3 = *(const float4*)(gp0 + CHUNK * 4 + 24 * 2048);
    __syncthreads();

    float h = 0.0f, ct = 0.0f;         // ct = -2log2e * c (pre-scaled cell)

    for (int n = 0; n < NCHUNK; ++n) {
        // publish chunk n+1 (regs loaded one chunk ago)
        const int wb = ((n + 1) & 1) * BUFF + wl0;
        *(float4*)&ldsx[wb + 0 * 8 * ROWF] = v0;
        *(float4*)&ldsx[wb + 1 * 8 * ROWF] = v1;
        *(float4*)&ldsx[wb + 2 * 8 * ROWF] = v2;
        *(float4*)&ldsx[wb + 3 * 8 * ROWF] = v3;
        // fetch chunk n+2 (wraps; junk on last iters, never consumed)
        const int t2 = ((n + 2) & (NCHUNK - 1)) * (CHUNK * 4);
        v0 = *(const float4*)(gp0 + t2);
        v1 = *(const float4*)(gp0 + t2 + 8 * 2048);
        v2 = *(const float4*)(gp0 + t2 + 16 * 2048);
        v3 = *(const float4*)(gp0 + t2 + 24 * 2048);

        const float* xr = &ldsx[(n & 1) * BUFF + e * ROWF];

        // xp pipeline head: x-projection for step 0 of this chunk
        float4 xc = *(const float4*)(xr);
        v2f xpIF = pk_fma_b(wihIF[0], xc.x, biasIF);
        v2f xpGO = pk_fma_b(wihGO[0], xc.x, biasGO);
        pk_fma_acc(xpIF, wihIF[1], xc.y);  pk_fma_acc(xpGO, wihGO[1], xc.y);
        pk_fma_acc(xpIF, wihIF[2], xc.z);  pk_fma_acc(xpGO, wihGO[2], xc.z);
        pk_fma_acc(xpIF, wihIF[3], xc.w);  pk_fma_acc(xpGO, wihGO[3], xc.w);

        #pragma unroll
        for (int t = 0; t < CHUNK; ++t) {
            // issue next step's x read early (wrap slot unused for pipeline)
            const float4 xn = *(const float4*)(xr + (((t + 1) & (CHUNK - 1)) * 4));

            // all-DPP h exchange (depth 2)
            const float s1 = dppf<0xB1>(h);
            const float s2 = dppf<0x4E>(h);
            const float s3 = dppf<0x1B>(h);
            const float s7 = dppf<0x141>(h);
            const float s4 = dppf<0x1B>(s7);
            const float s5 = dppf<0x4E>(s7);
            const float s6 = dppf<0xB1>(s7);

            // h-projection; this step's xp (precomputed) in the chain heads
            v2f aIF = pk_fma_b(whhIF[0], h,  xpIF);
            v2f bIF = pk_mul_b(whhIF[1], s1);
            v2f aGO = pk_fma_b(whhGO[0], h,  xpGO);
            v2f bGO = pk_mul_b(whhGO[1], s1);
            pk_fma_acc(aIF, whhIF[2], s2);    pk_fma_acc(aGO, whhGO[2], s2);
            pk_fma_acc(bIF, whhIF[3], s3);    pk_fma_acc(bGO, whhGO[3], s3);
            pk_fma_acc(aIF, whhIF[4], s4);    pk_fma_acc(aGO, whhGO[4], s4);
            pk_fma_acc(bIF, whhIF[5], s5);    pk_fma_acc(bGO, whhGO[5], s5);
            pk_fma_acc(aIF, whhIF[6], s6);    pk_fma_acc(aGO, whhGO[6], s6);
            pk_fma_acc(bIF, whhIF[7], s7);    pk_fma_acc(bGO, whhGO[7], s7);
            const v2f gIF = pk_add2(aIF, bIF);  // (ãi, ãf)
            const v2f gGO = pk_add2(aGO, bGO);  // (ãg, ão)

            // gate exps (pipeline through the trans unit)
            const float eI = __builtin_amdgcn_exp2f(gIF.x);
            const float eF = __builtin_amdgcn_exp2f(gIF.y);
            const float eG = __builtin_amdgcn_exp2f(gGO.x);
            const float eO = __builtin_amdgcn_exp2f(gGO.y);

            // ---- FILLER parked in the trans-latency bubble: next step's
            // x-projection (h-independent). Skipped on the chunk's last step
            // (recomputed at next chunk's head).
            if (t < CHUNK - 1) {
                v2f nIF = pk_fma_b(wihIF[0], xn.x, biasIF);
                v2f nGO = pk_fma_b(wihGO[0], xn.x, biasGO);
                pk_fma_acc(nIF, wihIF[1], xn.y);  pk_fma_acc(nGO, wihGO[1], xn.y);
                pk_fma_acc(nIF, wihIF[2], xn.z);  pk_fma_acc(nGO, wihGO[2], xn.z);
                pk_fma_acc(nIF, wihIF[3], xn.w);  pk_fma_acc(nGO, wihGO[3], xn.w);
                xpIF = nIF; xpGO = nGO;
            }

            // tail: 2 rcps total for gates (R3-combine, exact), 1 for cell
            const float qI = 1.0f + eI;
            const float qG = 1.0f + eG;
            const float qF = 1.0f + eF;
            const float qO = 1.0f + eO;
            const float P  = qI * qG;
            const float R3 = __builtin_amdgcn_rcpf(P * qF);
            const float f_ = P * R3;                      // sigmoid(af)
            const float ig = fmaf(eG, P2L, n2L) * (qF * R3);  // -2log2e*i*g
            ct = fmaf(f_, ct, ig);
            const float eC = __builtin_amdgcn_exp2f(ct);
            const float RC = __builtin_amdgcn_rcpf(qO * (1.0f + eC));
            h = (1.0f - eC) * RC;                         // o * tanh(c)
        }
        __syncthreads();
    }

    // out = h . W_fc + b_fc, reduced over the 8-lane group
    float pr = h * W_fc[j];
    pr += __shfl_xor(pr, 1);
    pr += __shfl_xor(pr, 2);
    pr += __shfl_xor(pr, 4);
    if (j == 0) out[blockIdx.x * EPB + e] = pr + b_fc[0];
}

extern "C" void kernel_launch(void* const* d_in, const int* in_sizes, int n_in,
                              void* d_out, int out_size, void* d_ws, size_t ws_size,
                              hipStream_t stream) {
    const float* x    = (const float*)d_in[0];
    const float* W_ih = (const float*)d_in[1];
    const float* W_hh = (const float*)d_in[2];
    const float* b_ih = (const float*)d_in[3];
    const float* b_hh = (const float*)d_in[4];
    const float* W_fc = (const float*)d_in[5];
    const float* b_fc = (const float*)d_in[6];
    float* out = (float*)d_out;

    const int B = in_sizes[0] / (T_STEPS * 4);   // 8192
    const int block = 256;
    const int grid = (B * 8) / block;            // 256 blocks
    lstm_kernel<<<grid, block, 0, stream>>>(x, W_ih, W_hh, b_ih, b_hh, W_fc, b_fc, out, B);
}